// Round 1
// baseline (1348.880 us; speedup 1.0000x reference)
//
#include <hip/hip_runtime.h>
#include <stdint.h>

// LSTM over N=512*321 independent univariate sequences, H=16, S=336, + FC(96).
// One wave handles 16 sequences. Per step: 4x mfma_f32_16x16x32_f16 computes
// pre[64 gate units][16 seqs] = W'_aug @ [h;x]_aug + bias(C operand, fp32 exact).
// Gates on VALU/trans pipe, h repacked to f16 pairs, 4 shuffles rebuild the
// next step's B fragment. No LDS, no __syncthreads, state in registers.

typedef _Float16 half8 __attribute__((ext_vector_type(8)));
typedef float floatx4 __attribute__((ext_vector_type(4)));

#define HH 16
#define SS 336
#define CCD 321
#define BBD 512
#define PPD 96
#define NSEQ (BBD * CCD)       // 164352
#define NTILES (NSEQ / 16)     // 10272, exact

static_assert(NSEQ % 16 == 0, "tile exactness");
static_assert(NTILES % 4 == 0, "block exactness");

__device__ __forceinline__ float fast_sigmoid(float x) {
    // 1/(1+e^-x): v_exp + v_rcp (2 trans, 2 valu)
    return __builtin_amdgcn_rcpf(1.0f + __expf(-x));
}
__device__ __forceinline__ float fast_tanh(float x) {
    // tanh(x) = 1 - 2/(e^{2x}+1); saturates correctly at +/-inf
    float e = __expf(2.0f * x);
    return 1.0f - 2.0f * __builtin_amdgcn_rcpf(e + 1.0f);
}

union U32H2 { uint32_t u; _Float16 h[2]; };
union BFrag { uint32_t u[4]; half8 v; };

__global__ __launch_bounds__(256) void lstm_fused(
    const float* __restrict__ x,      // [B,S,C]
    const float* __restrict__ W_ih,   // [64,1]
    const float* __restrict__ W_hh,   // [64,16]
    const float* __restrict__ b_ih,   // [64]
    const float* __restrict__ b_hh,   // [64]
    const float* __restrict__ W_fc,   // [96,16]
    const float* __restrict__ b_fc,   // [96]
    float* __restrict__ out)          // [B,96,C]
{
    const int lane = (int)(threadIdx.x & 63u);
    const int wid  = (int)(threadIdx.x >> 6u);
    const int tile = (int)blockIdx.x * 4 + wid;
    if (tile >= NTILES) return;

    const int n16 = lane & 15;   // sequence within tile (B col / D col / A row)
    const int g   = lane >> 4;   // k-group (A/B), row-group (C/D)

    const int n = tile * 16 + n16;       // global sequence id = b*C + c
    const int b = n / CCD;
    const int c = n - b * CCD;

    // ---- A fragments: W'[j][k], j = gate unit (row m = l&15 within tile t),
    //      k = g*8 + i; k<16 -> W_hh, k==16 -> W_ih, else 0. f16.
    half8 a_frag[4];
    #pragma unroll
    for (int t = 0; t < 4; ++t) {
        const int j = t * 16 + n16;
        #pragma unroll
        for (int i = 0; i < 8; ++i) {
            const int k = g * 8 + i;
            float w = 0.0f;
            if (k < 16)       w = W_hh[j * 16 + k];
            else if (k == 16) w = W_ih[j];
            a_frag[t][i] = (_Float16)w;
        }
    }
    // ---- bias via C operand (exact fp32): row j' = 16t + g*4 + r
    floatx4 bias_frag[4];
    #pragma unroll
    for (int t = 0; t < 4; ++t) {
        #pragma unroll
        for (int r = 0; r < 4; ++r) {
            const int j = t * 16 + g * 4 + r;
            bias_frag[t][r] = b_ih[j] + b_hh[j];
        }
    }

    // shuffle selectors: lane (n16,g) pulls h-packs from lanes (n16, 2g) and (n16, 2g+1)
    const int selA = n16 + ((g << 5) & 63);  // g=0 -> n16, g=1 -> n16+32 (g>=2 don't care, kept in range)
    const int selB = selA + 16;

    uint32_t hv0 = 0u, hv1 = 0u;   // packed f16 pairs: (h[4g],h[4g+1]), (h[4g+2],h[4g+3])
    float cst[4] = {0.f, 0.f, 0.f, 0.f};

    const float* xptr = x + (size_t)b * (SS * CCD) + c;
    float xcur = xptr[0];

    for (int s = 0; s < SS; ++s) {
        // prefetch next step's x (independent of the serial chain)
        float xnext = (s + 1 < SS) ? xptr[(s + 1) * CCD] : 0.0f;

        // rebuild B fragment (h_aug columns) from previous h
        uint32_t s0 = (uint32_t)__shfl((int)hv0, selA, 64);
        uint32_t s1 = (uint32_t)__shfl((int)hv1, selA, 64);
        uint32_t s2 = (uint32_t)__shfl((int)hv0, selB, 64);
        uint32_t s3 = (uint32_t)__shfl((int)hv1, selB, 64);

        U32H2 xp; xp.h[0] = (_Float16)xcur; xp.h[1] = (_Float16)0.0f;

        BFrag bf;
        bf.u[0] = (g < 2) ? s0 : ((g == 2) ? xp.u : 0u);
        bf.u[1] = (g < 2) ? s1 : 0u;
        bf.u[2] = (g < 2) ? s2 : 0u;
        bf.u[3] = (g < 2) ? s3 : 0u;

        floatx4 ai = __builtin_amdgcn_mfma_f32_16x16x32_f16(a_frag[0], bf.v, bias_frag[0], 0, 0, 0);
        floatx4 af = __builtin_amdgcn_mfma_f32_16x16x32_f16(a_frag[1], bf.v, bias_frag[1], 0, 0, 0);
        floatx4 ag = __builtin_amdgcn_mfma_f32_16x16x32_f16(a_frag[2], bf.v, bias_frag[2], 0, 0, 0);
        floatx4 ao = __builtin_amdgcn_mfma_f32_16x16x32_f16(a_frag[3], bf.v, bias_frag[3], 0, 0, 0);

        float hn[4];
        #pragma unroll
        for (int r = 0; r < 4; ++r) {
            float iv = fast_sigmoid(ai[r]);
            float fv = fast_sigmoid(af[r]);
            float gv = fast_tanh(ag[r]);
            float ov = fast_sigmoid(ao[r]);
            float cc = fv * cst[r] + iv * gv;
            cst[r] = cc;
            hn[r] = ov * fast_tanh(cc);
        }

        U32H2 p0, p1;
        p0.h[0] = (_Float16)hn[0]; p0.h[1] = (_Float16)hn[1];
        p1.h[0] = (_Float16)hn[2]; p1.h[1] = (_Float16)hn[3];
        hv0 = p0.u; hv1 = p1.u;
        xcur = xnext;
    }

    // ---- FC head: pred[p][n] = W_fc @ h_last + b_fc, 6 tiles of 16 rows
    uint32_t s0 = (uint32_t)__shfl((int)hv0, selA, 64);
    uint32_t s1 = (uint32_t)__shfl((int)hv1, selA, 64);
    uint32_t s2 = (uint32_t)__shfl((int)hv0, selB, 64);
    uint32_t s3 = (uint32_t)__shfl((int)hv1, selB, 64);

    BFrag bfc;
    bfc.u[0] = (g < 2) ? s0 : 0u;
    bfc.u[1] = (g < 2) ? s1 : 0u;
    bfc.u[2] = (g < 2) ? s2 : 0u;
    bfc.u[3] = (g < 2) ? s3 : 0u;

    const size_t obase = (size_t)b * (PPD * CCD) + c;
    #pragma unroll
    for (int t = 0; t < 6; ++t) {
        half8 afc;
        #pragma unroll
        for (int i = 0; i < 8; ++i) {
            const int k = g * 8 + i;
            float w = (k < 16) ? W_fc[(t * 16 + n16) * 16 + k] : 0.0f;
            afc[i] = (_Float16)w;
        }
        floatx4 cf;
        #pragma unroll
        for (int r = 0; r < 4; ++r) cf[r] = b_fc[t * 16 + g * 4 + r];

        floatx4 d = __builtin_amdgcn_mfma_f32_16x16x32_f16(afc, bfc.v, cf, 0, 0, 0);

        #pragma unroll
        for (int r = 0; r < 4; ++r) {
            const int p = t * 16 + g * 4 + r;
            out[obase + (size_t)p * CCD] = d[r];
        }
    }
}

extern "C" void kernel_launch(void* const* d_in, const int* in_sizes, int n_in,
                              void* d_out, int out_size, void* d_ws, size_t ws_size,
                              hipStream_t stream) {
    const float* x    = (const float*)d_in[0];
    const float* W_ih = (const float*)d_in[1];
    const float* W_hh = (const float*)d_in[2];
    const float* b_ih = (const float*)d_in[3];
    const float* b_hh = (const float*)d_in[4];
    const float* W_fc = (const float*)d_in[5];
    const float* b_fc = (const float*)d_in[6];
    float* out = (float*)d_out;

    dim3 grid(NTILES / 4);   // 2568 blocks
    dim3 block(256);         // 4 waves/block, 1 tile (16 seqs) per wave
    hipLaunchKernelGGL(lstm_fused, grid, block, 0, stream,
                       x, W_ih, W_hh, b_ih, b_hh, W_fc, b_fc, out);
}

// Round 3
// 1189.710 us; speedup vs baseline: 1.1338x; 1.1338x over previous
//
#include <hip/hip_runtime.h>
#include <stdint.h>

// LSTM over N=512*321 independent univariate sequences, H=16, S=336, + FC(96).
// One wave = 16 sequences. Per step: 4x mfma_f32_16x16x32_f16 computes
// pre[64 gate units][16 seqs] in TABLE-INDEX SPACE (scale+offset folded into
// the f16 A-fragment weights and the fp32 C-operand bias). Activations are
// LDS lerp-table lookups (sigma and tanh, 1024 entries each, value+slope),
// replacing exp+rcp on the quarter-rate trans pipe with 5 VALU + 1 ds_read_b64.
// State (c fp32 x4, h packed f16 x2) lives in registers; h transpose via 4
// ds_bpermute shuffles.

typedef _Float16 half8 __attribute__((ext_vector_type(8)));
typedef float floatx4 __attribute__((ext_vector_type(4)));

#define HH 16
#define SS 336
#define CCD 321
#define BBD 512
#define PPD 96
#define NSEQ (BBD * CCD)       // 164352
#define NTILES (NSEQ / 16)     // 10272, exact

#define TABN 1024
#define SIG_SCALE 64.0f        // 1024/16 -> sigma domain [-8, 8]
#define TANH_SCALE 128.0f      // 1024/8  -> tanh  domain [-4, 4]
#define IDX_OFF 512.0f
#define IDX_MAX 1022.995f      // clamp so i+1 (slope endpoint) stays in range

static_assert(NSEQ % 16 == 0, "tile exactness");
static_assert(NTILES % 4 == 0, "block exactness");

union U32H2 { uint32_t u; _Float16 h[2]; };
union BFrag { uint32_t u[4]; half8 v; };

// clamp + split + lerp from a (value, slope) table. y is already in index space.
__device__ __forceinline__ float lut(const float2* __restrict__ tab, float y) {
    y = __builtin_amdgcn_fmed3f(y, 0.0f, IDX_MAX);   // clamp (saturation regions)
    float fr = __builtin_amdgcn_fractf(y);           // y - floor(y), y >= 0
    int i = (int)y;                                  // trunc == floor for y >= 0
    float2 e = tab[i];                               // ds_read_b64
    return fmaf(fr, e.y, e.x);                       // value + fr * slope
}

__global__ __launch_bounds__(256) void lstm_fused(
    const float* __restrict__ x,      // [B,S,C]
    const float* __restrict__ W_ih,   // [64,1]
    const float* __restrict__ W_hh,   // [64,16]
    const float* __restrict__ b_ih,   // [64]
    const float* __restrict__ b_hh,   // [64]
    const float* __restrict__ W_fc,   // [96,16]
    const float* __restrict__ b_fc,   // [96]
    float* __restrict__ out)          // [B,96,C]
{
    __shared__ float2 sig_tab[TABN];
    __shared__ float2 tanh_tab[TABN];

    // ---- build activation tables (accurate libm, once per block) ----
    for (int i = (int)threadIdx.x; i < TABN; i += 256) {
        float x0 = ((float)i       - IDX_OFF) / SIG_SCALE;
        float x1 = ((float)(i + 1) - IDX_OFF) / SIG_SCALE;
        float s0 = 1.0f / (1.0f + expf(-x0));
        float s1 = 1.0f / (1.0f + expf(-x1));
        sig_tab[i] = make_float2(s0, s1 - s0);
        float u0 = ((float)i       - IDX_OFF) / TANH_SCALE;
        float u1 = ((float)(i + 1) - IDX_OFF) / TANH_SCALE;
        float t0 = tanhf(u0);
        float t1 = tanhf(u1);
        tanh_tab[i] = make_float2(t0, t1 - t0);
    }
    __syncthreads();

    const int lane = (int)(threadIdx.x & 63u);
    const int wid  = (int)(threadIdx.x >> 6u);
    const int tile = (int)blockIdx.x * 4 + wid;
    if (tile >= NTILES) return;

    const int n16 = lane & 15;   // sequence within tile (B col / D col / A row)
    const int g   = lane >> 4;   // k-group (A/B), row-group (C/D)

    const int n = tile * 16 + n16;       // global sequence id = b*C + c
    const int b = n / CCD;
    const int c = n - b * CCD;

    // per-gate-tile index-space scale: i,f use sigma table (64), g uses tanh
    // table (128), o uses sigma table (64)
    const float gate_scale[4] = { SIG_SCALE, SIG_SCALE, TANH_SCALE, SIG_SCALE };

    // ---- A fragments: S_t * W'[j][k]; j = gate unit, k = g*8 + i;
    //      k<16 -> W_hh, k==16 -> W_ih, else 0. f16.
    half8 a_frag[4];
    #pragma unroll
    for (int t = 0; t < 4; ++t) {
        const int j = t * 16 + n16;
        const float sc = gate_scale[t];
        #pragma unroll
        for (int i = 0; i < 8; ++i) {
            const int k = g * 8 + i;
            float w = 0.0f;
            if (k < 16)       w = W_hh[j * 16 + k];
            else if (k == 16) w = W_ih[j];
            a_frag[t][i] = (_Float16)(w * sc);
        }
    }
    // ---- bias via C operand (exact fp32, index space): S_t * b + 512
    floatx4 bias_frag[4];
    #pragma unroll
    for (int t = 0; t < 4; ++t) {
        #pragma unroll
        for (int r = 0; r < 4; ++r) {
            const int j = t * 16 + g * 4 + r;
            bias_frag[t][r] = (b_ih[j] + b_hh[j]) * gate_scale[t] + IDX_OFF;
        }
    }

    // shuffle selectors: lane (n16,g) pulls h-packs from lanes (n16, 2g) and (n16, 2g+1)
    const int selA = n16 + ((g << 5) & 63);
    const int selB = selA + 16;

    uint32_t hv0 = 0u, hv1 = 0u;   // packed f16 pairs: (h[4g],h[4g+1]), (h[4g+2],h[4g+3])
    float cst[4] = {0.f, 0.f, 0.f, 0.f};

    const float* xptr = x + (size_t)b * (SS * CCD) + c;
    float xcur = xptr[0];

    for (int s = 0; s < SS; ++s) {
        float xnext = (s + 1 < SS) ? xptr[(s + 1) * CCD] : 0.0f;

        // rebuild B fragment (h_aug columns) from previous h
        uint32_t s0 = (uint32_t)__shfl((int)hv0, selA, 64);
        uint32_t s1 = (uint32_t)__shfl((int)hv1, selA, 64);
        uint32_t s2 = (uint32_t)__shfl((int)hv0, selB, 64);
        uint32_t s3 = (uint32_t)__shfl((int)hv1, selB, 64);

        U32H2 xp; xp.h[0] = (_Float16)xcur; xp.h[1] = (_Float16)0.0f;

        BFrag bf;
        bf.u[0] = (g < 2) ? s0 : ((g == 2) ? xp.u : 0u);
        bf.u[1] = (g < 2) ? s1 : 0u;
        bf.u[2] = (g < 2) ? s2 : 0u;
        bf.u[3] = (g < 2) ? s3 : 0u;

        // pre-activations in table-index space
        floatx4 ai = __builtin_amdgcn_mfma_f32_16x16x32_f16(a_frag[0], bf.v, bias_frag[0], 0, 0, 0);
        floatx4 af = __builtin_amdgcn_mfma_f32_16x16x32_f16(a_frag[1], bf.v, bias_frag[1], 0, 0, 0);
        floatx4 ag = __builtin_amdgcn_mfma_f32_16x16x32_f16(a_frag[2], bf.v, bias_frag[2], 0, 0, 0);
        floatx4 ao = __builtin_amdgcn_mfma_f32_16x16x32_f16(a_frag[3], bf.v, bias_frag[3], 0, 0, 0);

        float hn[4];
        #pragma unroll
        for (int r = 0; r < 4; ++r) {
            float iv = lut(sig_tab,  ai[r]);
            float fv = lut(sig_tab,  af[r]);
            float gv = lut(tanh_tab, ag[r]);
            float ov = lut(sig_tab,  ao[r]);
            float cc = fmaf(fv, cst[r], iv * gv);
            cst[r] = cc;
            float tc = lut(tanh_tab, fmaf(cc, TANH_SCALE, IDX_OFF));
            hn[r] = ov * tc;
        }

        U32H2 p0, p1;
        p0.h[0] = (_Float16)hn[0]; p0.h[1] = (_Float16)hn[1];
        p1.h[0] = (_Float16)hn[2]; p1.h[1] = (_Float16)hn[3];
        hv0 = p0.u; hv1 = p1.u;
        xcur = xnext;
    }

    // ---- FC head: pred[p][n] = W_fc @ h_last + b_fc, 6 tiles of 16 rows
    uint32_t s0 = (uint32_t)__shfl((int)hv0, selA, 64);
    uint32_t s1 = (uint32_t)__shfl((int)hv1, selA, 64);
    uint32_t s2 = (uint32_t)__shfl((int)hv0, selB, 64);
    uint32_t s3 = (uint32_t)__shfl((int)hv1, selB, 64);

    BFrag bfc;
    bfc.u[0] = (g < 2) ? s0 : 0u;
    bfc.u[1] = (g < 2) ? s1 : 0u;
    bfc.u[2] = (g < 2) ? s2 : 0u;
    bfc.u[3] = (g < 2) ? s3 : 0u;

    const size_t obase = (size_t)b * (PPD * CCD) + c;
    #pragma unroll
    for (int t = 0; t < 6; ++t) {
        half8 afc;
        #pragma unroll
        for (int i = 0; i < 8; ++i) {
            const int k = g * 8 + i;
            float w = (k < 16) ? W_fc[(t * 16 + n16) * 16 + k] : 0.0f;
            afc[i] = (_Float16)w;
        }
        floatx4 cf;
        #pragma unroll
        for (int r = 0; r < 4; ++r) cf[r] = b_fc[t * 16 + g * 4 + r];

        floatx4 d = __builtin_amdgcn_mfma_f32_16x16x32_f16(afc, bfc.v, cf, 0, 0, 0);

        #pragma unroll
        for (int r = 0; r < 4; ++r) {
            const int p = t * 16 + g * 4 + r;
            out[obase + (size_t)p * CCD] = d[r];
        }
    }
}

extern "C" void kernel_launch(void* const* d_in, const int* in_sizes, int n_in,
                              void* d_out, int out_size, void* d_ws, size_t ws_size,
                              hipStream_t stream) {
    const float* x    = (const float*)d_in[0];
    const float* W_ih = (const float*)d_in[1];
    const float* W_hh = (const float*)d_in[2];
    const float* b_ih = (const float*)d_in[3];
    const float* b_hh = (const float*)d_in[4];
    const float* W_fc = (const float*)d_in[5];
    const float* b_fc = (const float*)d_in[6];
    float* out = (float*)d_out;

    dim3 grid(NTILES / 4);   // 2568 blocks
    dim3 block(256);         // 4 waves/block, 1 tile (16 seqs) per wave
    hipLaunchKernelGGL(lstm_fused, grid, block, 0, stream,
                       x, W_ih, W_hh, b_ih, b_hh, W_fc, b_fc, out);
}